// Round 7
// baseline (620.492 us; speedup 1.0000x reference)
//
#include <hip/hip_runtime.h>
#include <hip/hip_cooperative_groups.h>
#include <hip/hip_fp16.h>
#include <math.h>

namespace cg = cooperative_groups;

#define NB 8
#define NS 2048
#define NN (NB*NS)       // 16384 nodes
#define NE (NN*16)       // 262144 edges
#define EPSF 1e-5f

typedef float  f32x4 __attribute__((ext_vector_type(4)));
typedef _Float16 f16x8 __attribute__((ext_vector_type(8)));
union F8 { f16x8 v; unsigned u[4]; };

__device__ __forceinline__ unsigned pk2h(float a, float b) {
    __half2 hh = __floats2half2_rn(a, b);
    unsigned u; __builtin_memcpy(&u, &hh, 4); return u;
}

struct Pm {
    const float* x; const int* srcv; const int* tgtv;
    const float* encW; const float* encB;
    const float* m1w; const float* m1b; const float* m2w; const float* m2b;
    const float* u1w; const float* u1b; const float* u2w; const float* u2b;
    const float* dw;  const float* db;
    float* out;
    float *h, *agg, *A, *Bm, *g0, *g1, *acc;
    int *deg, *ssrc;
};

// LDS union across phases; max member (upd) = 44 KB -> 3 blocks/CU.
struct __align__(16) SU {
    union {
        struct { _Float16 w1[8192]; _Float16 w2[4096];
                 float hid[4][16*68]; float sum[4][64]; float sq[4][64]; } upd;
        struct { _Float16 wp[8192]; float encw[256]; float encb[64];
                 float mean[64]; float rstd[64]; } pre;
        struct { float w[4096]; } edge;
        struct { float xs[8192]; float ws[4]; } t3;
        struct { float m[64]; float r[64]; float wd[256]; float ws[4]; } dec;
    } u;
};

// (enc for l==0 | instance-norm for l>0) -> h; A = h@W1a+b1; Bm = h@W1b.
__device__ void pre_phase(const Pm& p, SU& s, int l)
{
    const int tid = threadIdx.x, blk = blockIdx.x;
    const float* W1 = p.m1w + l*8192;
    const float* B1 = p.m1b + l*64;
    const float* gin = ((l+1)&1) ? p.g1 : p.g0;   // l1->g0, l2->g1
    float* gz = (l&1) ? p.g1 : p.g0;              // l1 zeroes g1, l2 zeroes g0
    for (int idx = tid; idx < 8192; idx += 256) {
        int k = idx >> 7, n = idx & 127;
        float val = (n < 64) ? W1[k*64 + n] : W1[(64+k)*64 + (n-64)];
        int ks = k >> 5, qd = (k >> 3) & 3, j = k & 7, nt = n >> 4, cl = n & 15;
        s.u.pre.wp[(((ks*8+nt)*4+qd)*16+cl)*8 + j] = (_Float16)val;
    }
    if (l == 0) {
        s.u.pre.encw[tid] = p.encW[tid & 255];
        if (tid < 64) s.u.pre.encb[tid] = p.encB[tid];
    } else if (blk == 0) {
        for (int i = tid; i < 2*NB*64; i += 256) gz[i] = 0.f;
    }
    __syncthreads();
    const int lane = tid & 63, wv = tid >> 6;
    const int col = lane & 15, quad = lane >> 4;
    float b1v[4];
    #pragma unroll
    for (int nt = 0; nt < 4; nt++) b1v[nt] = B1[nt*16+col];
    for (int t0 = blk*4; t0 < NN/16; t0 += gridDim.x*4) {
        const int n0w = (t0 + wv)*16;
        float xv[16];
        if (l) {
            __syncthreads();
            if (tid < 64) {
                int b = t0 >> 7;
                float sv = gin[b*64 + tid];
                float qq = gin[NB*64 + b*64 + tid];
                float mean = sv * (1.f/NS);
                float var = qq * (1.f/NS) - mean*mean;
                s.u.pre.mean[tid] = mean;
                s.u.pre.rstd[tid] = rsqrtf(var + EPSF);
            }
            __syncthreads();
            float* hp = &p.h[(size_t)(n0w+col)*64 + quad*8];
            *(float4*)&xv[0]  = *(const float4*)&hp[0];
            *(float4*)&xv[4]  = *(const float4*)&hp[4];
            *(float4*)&xv[8]  = *(const float4*)&hp[32];
            *(float4*)&xv[12] = *(const float4*)&hp[36];
            #pragma unroll
            for (int j = 0; j < 8; j++) {
                int f = quad*8 + j;
                xv[j] = (xv[j] - s.u.pre.mean[f]) * s.u.pre.rstd[f];
            }
            #pragma unroll
            for (int j = 0; j < 8; j++) {
                int f = 32 + quad*8 + j;
                xv[8+j] = (xv[8+j] - s.u.pre.mean[f]) * s.u.pre.rstd[f];
            }
            *(float4*)&hp[0]  = *(float4*)&xv[0];
            *(float4*)&hp[4]  = *(float4*)&xv[4];
            *(float4*)&hp[32] = *(float4*)&xv[8];
            *(float4*)&hp[36] = *(float4*)&xv[12];
        } else {
            const int n = n0w + col;
            float4 x4 = *(const float4*)&p.x[(size_t)n*4];
            #pragma unroll
            for (int hh = 0; hh < 2; hh++)
                #pragma unroll
                for (int j = 0; j < 8; j++) {
                    int f = hh*32 + quad*8 + j;
                    float v = s.u.pre.encb[f];
                    v = fmaf(x4.x, s.u.pre.encw[f],      v);
                    v = fmaf(x4.y, s.u.pre.encw[64+f],   v);
                    v = fmaf(x4.z, s.u.pre.encw[128+f],  v);
                    v = fmaf(x4.w, s.u.pre.encw[192+f],  v);
                    xv[hh*8+j] = v;
                }
            float* hp = &p.h[(size_t)n*64 + quad*8];
            *(float4*)&hp[0]  = *(float4*)&xv[0];
            *(float4*)&hp[4]  = *(float4*)&xv[4];
            *(float4*)&hp[32] = *(float4*)&xv[8];
            *(float4*)&hp[36] = *(float4*)&xv[12];
        }
        F8 af0, af1;
        af0.u[0] = pk2h(xv[0],  xv[1]);  af0.u[1] = pk2h(xv[2],  xv[3]);
        af0.u[2] = pk2h(xv[4],  xv[5]);  af0.u[3] = pk2h(xv[6],  xv[7]);
        af1.u[0] = pk2h(xv[8],  xv[9]);  af1.u[1] = pk2h(xv[10], xv[11]);
        af1.u[2] = pk2h(xv[12], xv[13]); af1.u[3] = pk2h(xv[14], xv[15]);
        #pragma unroll
        for (int nt = 0; nt < 8; nt++) {
            f32x4 acc = {0.f,0.f,0.f,0.f};
            F8 bf; bf.v = *(const f16x8*)&s.u.pre.wp[(((0*8+nt)*4+quad)*16+col)*8];
            acc = __builtin_amdgcn_mfma_f32_16x16x32_f16(af0.v, bf.v, acc, 0, 0, 0);
            bf.v = *(const f16x8*)&s.u.pre.wp[(((1*8+nt)*4+quad)*16+col)*8];
            acc = __builtin_amdgcn_mfma_f32_16x16x32_f16(af1.v, bf.v, acc, 0, 0, 0);
            if (nt < 4) {
                float bb = b1v[nt];
                p.A[(size_t)(n0w + quad*4 + 0)*64 + nt*16 + col] = acc.x + bb;
                p.A[(size_t)(n0w + quad*4 + 1)*64 + nt*16 + col] = acc.y + bb;
                p.A[(size_t)(n0w + quad*4 + 2)*64 + nt*16 + col] = acc.z + bb;
                p.A[(size_t)(n0w + quad*4 + 3)*64 + nt*16 + col] = acc.w + bb;
            } else {
                p.Bm[(size_t)(n0w + quad*4 + 0)*64 + (nt-4)*16 + col] = acc.x;
                p.Bm[(size_t)(n0w + quad*4 + 1)*64 + (nt-4)*16 + col] = acc.y;
                p.Bm[(size_t)(n0w + quad*4 + 2)*64 + (nt-4)*16 + col] = acc.z;
                p.Bm[(size_t)(n0w + quad*4 + 3)*64 + (nt-4)*16 + col] = acc.w;
            }
        }
    }
}

// slotted-CSR edge kernel: one wave per target, plain stores.
__device__ void edge_phase(const Pm& p, SU& s, int l)
{
    const int tid = threadIdx.x;
    const float* W2 = p.m2w + l*4096;
    const float* B2 = p.m2b + l*64;
    for (int i = tid; i < 4096; i += 256) s.u.edge.w[i] = W2[i];
    __syncthreads();
    const int lane = tid & 63;
    const int col = lane & 15, quad = lane >> 4;
    F8 bf[4][2];
    #pragma unroll
    for (int nt = 0; nt < 4; nt++)
        #pragma unroll
        for (int ks = 0; ks < 2; ks++)
            #pragma unroll
            for (int jj = 0; jj < 4; jj++) {
                int k = ks*32 + quad*8 + jj*2;
                bf[nt][ks].u[jj] = pk2h(s.u.edge.w[k*64 + nt*16 + col],
                                        s.u.edge.w[(k+1)*64 + nt*16 + col]);
            }
    float b2v[4];
    #pragma unroll
    for (int nt = 0; nt < 4; nt++) b2v[nt] = B2[nt*16 + col];
    const int wid = blockIdx.x*4 + (tid >> 6);
    const int nwv = gridDim.x*4;
    for (int t = wid; t < NN; t += nwv) {
        int cnt = p.deg[t]; if (cnt > 64) cnt = 64;
        int base = t*64;
        const float* ar = &p.A[(size_t)t*64 + quad*8];
        float4 a0 = *(const float4*)&ar[0];
        float4 a1 = *(const float4*)&ar[4];
        float4 a2 = *(const float4*)&ar[32];
        float4 a3 = *(const float4*)&ar[36];
        float cs[4] = {0.f, 0.f, 0.f, 0.f};
        for (int s0 = 0; s0 < cnt; s0 += 16) {
            int v = cnt - s0;
            int cc = col < v-1 ? col : v-1;
            int sr = p.ssrc[base + s0 + cc];
            const float* br = &p.Bm[(size_t)sr*64 + quad*8];
            float4 b0 = *(const float4*)&br[0];
            float4 b1 = *(const float4*)&br[4];
            float4 b2_ = *(const float4*)&br[32];
            float4 b3 = *(const float4*)&br[36];
            F8 af0, af1;
            af0.u[0] = pk2h(fmaxf(a0.x+b0.x,0.f), fmaxf(a0.y+b0.y,0.f));
            af0.u[1] = pk2h(fmaxf(a0.z+b0.z,0.f), fmaxf(a0.w+b0.w,0.f));
            af0.u[2] = pk2h(fmaxf(a1.x+b1.x,0.f), fmaxf(a1.y+b1.y,0.f));
            af0.u[3] = pk2h(fmaxf(a1.z+b1.z,0.f), fmaxf(a1.w+b1.w,0.f));
            af1.u[0] = pk2h(fmaxf(a2.x+b2_.x,0.f), fmaxf(a2.y+b2_.y,0.f));
            af1.u[1] = pk2h(fmaxf(a2.z+b2_.z,0.f), fmaxf(a2.w+b2_.w,0.f));
            af1.u[2] = pk2h(fmaxf(a3.x+b3.x,0.f), fmaxf(a3.y+b3.y,0.f));
            af1.u[3] = pk2h(fmaxf(a3.z+b3.z,0.f), fmaxf(a3.w+b3.w,0.f));
            #pragma unroll
            for (int nt = 0; nt < 4; nt++) {
                f32x4 acc = __builtin_amdgcn_mfma_f32_16x16x32_f16(
                                af0.v, bf[nt][0].v, (f32x4){0.f,0.f,0.f,0.f}, 0, 0, 0);
                acc = __builtin_amdgcn_mfma_f32_16x16x32_f16(
                                af1.v, bf[nt][1].v, acc, 0, 0, 0);
                float r0 = (quad*4+0 < v) ? fmaxf(acc.x + b2v[nt], 0.f) : 0.f;
                float r1 = (quad*4+1 < v) ? fmaxf(acc.y + b2v[nt], 0.f) : 0.f;
                float r2 = (quad*4+2 < v) ? fmaxf(acc.z + b2v[nt], 0.f) : 0.f;
                float r3 = (quad*4+3 < v) ? fmaxf(acc.w + b2v[nt], 0.f) : 0.f;
                cs[nt] += (r0 + r1) + (r2 + r3);
            }
        }
        #pragma unroll
        for (int nt = 0; nt < 4; nt++) {
            float vv = cs[nt];
            vv += __shfl_down(vv, 32, 64);
            vv += __shfl_down(vv, 16, 64);
            cs[nt] = vv;
        }
        if (lane < 16) {
            p.agg[(size_t)t*64 +  0 + lane] = cs[0];
            p.agg[(size_t)t*64 + 16 + lane] = cs[1];
            p.agg[(size_t)t*64 + 32 + lane] = cs[2];
            p.agg[(size_t)t*64 + 48 + lane] = cs[3];
        }
    }
}

// MFMA update MLP + instance-norm stats.
__device__ void upd_phase(const Pm& p, SU& s, int l)
{
    const int tid = threadIdx.x, blk = blockIdx.x;
    const float* W1 = p.u1w + l*8192; const float* B1 = p.u1b + l*64;
    const float* W2 = p.u2w + l*4096; const float* B2 = p.u2b + l*64;
    float* gout = (l&1) ? p.g1 : p.g0;
    for (int idx = tid; idx < 8192; idx += 256) {
        int k = idx >> 6, n = idx & 63;
        int ks = k >> 5, qd = (k >> 3) & 3, j = k & 7, nt = n >> 4, cl = n & 15;
        s.u.upd.w1[(((ks*4+nt)*4+qd)*16+cl)*8 + j] = (_Float16)W1[idx];
    }
    for (int idx = tid; idx < 4096; idx += 256) {
        int k = idx >> 6, n = idx & 63;
        int ks = k >> 5, qd = (k >> 3) & 3, j = k & 7, nt = n >> 4, cl = n & 15;
        s.u.upd.w2[(((ks*4+nt)*4+qd)*16+cl)*8 + j] = (_Float16)W2[idx];
    }
    __syncthreads();
    const int lane = tid & 63, wv = tid >> 6;
    const int col = lane & 15, quad = lane >> 4;
    float b1v[4], b2v[4];
    #pragma unroll
    for (int nt = 0; nt < 4; nt++) { b1v[nt] = B1[nt*16+col]; b2v[nt] = B2[nt*16+col]; }
    for (int t0 = blk*4; t0 < NN/16; t0 += gridDim.x*4) {
        const int n0w = (t0 + wv)*16;
        const float* hp = &p.h[(size_t)(n0w+col)*64 + quad*8];
        const float* ap = &p.agg[(size_t)(n0w+col)*64 + quad*8];
        float4 h0 = *(const float4*)&hp[0];
        float4 h1 = *(const float4*)&hp[4];
        float4 h2 = *(const float4*)&hp[32];
        float4 h3 = *(const float4*)&hp[36];
        float4 g0 = *(const float4*)&ap[0];
        float4 g1 = *(const float4*)&ap[4];
        float4 g2 = *(const float4*)&ap[32];
        float4 g3 = *(const float4*)&ap[36];
        F8 af[4];
        af[0].u[0] = pk2h(h0.x, h0.y); af[0].u[1] = pk2h(h0.z, h0.w);
        af[0].u[2] = pk2h(h1.x, h1.y); af[0].u[3] = pk2h(h1.z, h1.w);
        af[1].u[0] = pk2h(h2.x, h2.y); af[1].u[1] = pk2h(h2.z, h2.w);
        af[1].u[2] = pk2h(h3.x, h3.y); af[1].u[3] = pk2h(h3.z, h3.w);
        af[2].u[0] = pk2h(g0.x, g0.y); af[2].u[1] = pk2h(g0.z, g0.w);
        af[2].u[2] = pk2h(g1.x, g1.y); af[2].u[3] = pk2h(g1.z, g1.w);
        af[3].u[0] = pk2h(g2.x, g2.y); af[3].u[1] = pk2h(g2.z, g2.w);
        af[3].u[2] = pk2h(g3.x, g3.y); af[3].u[3] = pk2h(g3.z, g3.w);
        float* hid = &s.u.upd.hid[wv][0];
        #pragma unroll
        for (int nt = 0; nt < 4; nt++) {
            f32x4 acc = {0.f,0.f,0.f,0.f};
            #pragma unroll
            for (int ks = 0; ks < 4; ks++) {
                F8 bf; bf.v = *(const f16x8*)&s.u.upd.w1[(((ks*4+nt)*4+quad)*16+col)*8];
                acc = __builtin_amdgcn_mfma_f32_16x16x32_f16(af[ks].v, bf.v, acc, 0, 0, 0);
            }
            hid[(quad*4+0)*68 + nt*16+col] = fmaxf(acc.x + b1v[nt], 0.f);
            hid[(quad*4+1)*68 + nt*16+col] = fmaxf(acc.y + b1v[nt], 0.f);
            hid[(quad*4+2)*68 + nt*16+col] = fmaxf(acc.z + b1v[nt], 0.f);
            hid[(quad*4+3)*68 + nt*16+col] = fmaxf(acc.w + b1v[nt], 0.f);
        }
        __syncthreads();
        const float* hr = &hid[col*68 + quad*8];
        float4 q0 = *(const float4*)&hr[0];
        float4 q1 = *(const float4*)&hr[4];
        float4 q2 = *(const float4*)&hr[32];
        float4 q3 = *(const float4*)&hr[36];
        F8 e0, e1;
        e0.u[0] = pk2h(q0.x, q0.y); e0.u[1] = pk2h(q0.z, q0.w);
        e0.u[2] = pk2h(q1.x, q1.y); e0.u[3] = pk2h(q1.z, q1.w);
        e1.u[0] = pk2h(q2.x, q2.y); e1.u[1] = pk2h(q2.z, q2.w);
        e1.u[2] = pk2h(q3.x, q3.y); e1.u[3] = pk2h(q3.z, q3.w);
        float ss[4], sq[4];
        #pragma unroll
        for (int nt = 0; nt < 4; nt++) {
            f32x4 acc = {0.f,0.f,0.f,0.f};
            F8 bf; bf.v = *(const f16x8*)&s.u.upd.w2[(((0*4+nt)*4+quad)*16+col)*8];
            acc = __builtin_amdgcn_mfma_f32_16x16x32_f16(e0.v, bf.v, acc, 0, 0, 0);
            bf.v = *(const f16x8*)&s.u.upd.w2[(((1*4+nt)*4+quad)*16+col)*8];
            acc = __builtin_amdgcn_mfma_f32_16x16x32_f16(e1.v, bf.v, acc, 0, 0, 0);
            float o0 = fmaxf(acc.x + b2v[nt], 0.f);
            float o1 = fmaxf(acc.y + b2v[nt], 0.f);
            float o2 = fmaxf(acc.z + b2v[nt], 0.f);
            float o3 = fmaxf(acc.w + b2v[nt], 0.f);
            p.h[(size_t)(n0w + quad*4 + 0)*64 + nt*16 + col] = o0;
            p.h[(size_t)(n0w + quad*4 + 1)*64 + nt*16 + col] = o1;
            p.h[(size_t)(n0w + quad*4 + 2)*64 + nt*16 + col] = o2;
            p.h[(size_t)(n0w + quad*4 + 3)*64 + nt*16 + col] = o3;
            ss[nt] = (o0 + o1) + (o2 + o3);
            sq[nt] = (o0*o0 + o1*o1) + (o2*o2 + o3*o3);
        }
        #pragma unroll
        for (int nt = 0; nt < 4; nt++) {
            float v = ss[nt];
            v += __shfl_down(v, 32, 64); v += __shfl_down(v, 16, 64);
            float w2 = sq[nt];
            w2 += __shfl_down(w2, 32, 64); w2 += __shfl_down(w2, 16, 64);
            if (lane < 16) { s.u.upd.sum[wv][nt*16+lane] = v; s.u.upd.sq[wv][nt*16+lane] = w2; }
        }
        __syncthreads();
        if (tid < 128) {
            int ch = tid & 63, hf = tid >> 6;
            int b = t0 >> 7;
            if (hf == 0) {
                float t_ = s.u.upd.sum[0][ch]+s.u.upd.sum[1][ch]+s.u.upd.sum[2][ch]+s.u.upd.sum[3][ch];
                atomicAdd(&gout[b*64 + ch], t_);
            } else {
                float t_ = s.u.upd.sq[0][ch]+s.u.upd.sq[1][ch]+s.u.upd.sq[2][ch]+s.u.upd.sq[3][ch];
                atomicAdd(&gout[NB*64 + b*64 + ch], t_);
            }
        }
        __syncthreads();
    }
}

// instance-norm + decode + sigmoid + t2 partial; X -> xbuf (=A) and out+1.
__device__ void dec_phase(const Pm& p, SU& s)
{
    const int tid = threadIdx.x, blk = blockIdx.x;
    for (int nb0 = blk*256; nb0 < NN; nb0 += gridDim.x*256) {
        const int n = nb0 + tid;
        const int b = nb0 >> 11;
        __syncthreads();
        if (tid < 64) {
            float sv = p.g0[b*64 + tid];
            float qq = p.g0[NB*64 + b*64 + tid];
            float mean = sv * (1.f/NS);
            float var = qq * (1.f/NS) - mean*mean;
            s.u.dec.m[tid] = mean; s.u.dec.r[tid] = rsqrtf(var + EPSF);
        }
        s.u.dec.wd[tid] = p.dw[tid & 255];
        __syncthreads();
        float a0 = p.db[0], a1 = p.db[1], a2 = p.db[2], a3 = p.db[3];
        const float* hr = p.h + (size_t)n*64;
        #pragma unroll 8
        for (int k = 0; k < 64; k++) {
            float v = (hr[k] - s.u.dec.m[k]) * s.u.dec.r[k];
            a0 = fmaf(v, s.u.dec.wd[k*4+0], a0);
            a1 = fmaf(v, s.u.dec.wd[k*4+1], a1);
            a2 = fmaf(v, s.u.dec.wd[k*4+2], a2);
            a3 = fmaf(v, s.u.dec.wd[k*4+3], a3);
        }
        float4 o;
        o.x = 1.f/(1.f + expf(-a0));
        o.y = 1.f/(1.f + expf(-a1));
        o.z = 1.f/(1.f + expf(-a2));
        o.w = 1.f/(1.f + expf(-a3));
        *(float4*)&p.A[(size_t)n*4] = o;      // xbuf alias
        p.out[1 + n*4 + 0] = o.x; p.out[1 + n*4 + 1] = o.y;
        p.out[1 + n*4 + 2] = o.z; p.out[1 + n*4 + 3] = o.w;
        float pr = (1.f-o.x*o.x)*(1.f-o.y*o.y)*(1.f-o.z*o.z)*(1.f-o.w*o.w);
        for (int offs = 32; offs; offs >>= 1) pr += __shfl_down(pr, offs, 64);
        if ((tid & 63) == 0) s.u.dec.ws[tid >> 6] = pr;
        __syncthreads();
        if (tid == 0)
            atomicAdd(&p.acc[0], s.u.dec.ws[0]+s.u.dec.ws[1]+s.u.dec.ws[2]+s.u.dec.ws[3]);
    }
}

// t3 pairwise term.
__device__ void t3_phase(const Pm& p, SU& s)
{
    const int tid = threadIdx.x, blk = blockIdx.x;
    for (int tl = blk; tl < 256; tl += gridDim.x) {
        const int b = tl >> 5, c = tl & 31;
        __syncthreads();
        const float* Xb = p.A + (size_t)b*NS*4;
        for (int i = tid; i < NS*4; i += 256) s.u.t3.xs[i] = Xb[i];
        __syncthreads();
        const float4* sX4 = (const float4*)s.u.t3.xs;
        const int il = tid & 63, wv = tid >> 6;
        float4 xi = sX4[c*64 + il];
        float acc = 0.f;
        #pragma unroll 4
        for (int ss = 0; ss < 512; ss++) {
            float4 xj = sX4[wv*512 + ss];
            acc += (1.f - fmaxf(xi.x, xj.x)) * (1.f - fmaxf(xi.y, xj.y))
                 * (1.f - fmaxf(xi.z, xj.z)) * (1.f - fmaxf(xi.w, xj.w));
        }
        for (int offs = 32; offs; offs >>= 1) acc += __shfl_down(acc, offs, 64);
        if (il == 0) s.u.t3.ws[wv] = acc;
        __syncthreads();
        if (tid == 0)
            atomicAdd(&p.acc[1], s.u.t3.ws[0]+s.u.t3.ws[1]+s.u.t3.ws[2]+s.u.t3.ws[3]);
    }
}

__global__ __launch_bounds__(256, 3) void k_mega(Pm p)
{
    cg::grid_group grid = cg::this_grid();
    __shared__ SU s;
    const int tid = threadIdx.x, blk = blockIdx.x;
    const int gid = blk*256 + tid, NT = gridDim.x*256;

    // P0: zero deg, g0, acc
    for (int i = gid; i < NN; i += NT) p.deg[i] = 0;
    for (int i = gid; i < 2*NB*64; i += NT) p.g0[i] = 0.f;
    if (gid < 4) p.acc[gid] = 0.f;
    grid.sync();

    // P1: slotted-CSR scatter + enc + A/B
    for (int e = gid; e < NE; e += NT) {
        int t = p.tgtv[e];
        int pos = atomicAdd(&p.deg[t], 1) & 63;
        p.ssrc[t*64 + pos] = p.srcv[e];
    }
    pre_phase(p, s, 0);
    grid.sync();

    for (int l = 0; l < 3; l++) {
        edge_phase(p, s, l);
        grid.sync();
        upd_phase(p, s, l);
        grid.sync();
        if (l < 2) {
            pre_phase(p, s, l+1);
            grid.sync();
        }
    }

    dec_phase(p, s);
    grid.sync();
    t3_phase(p, s);
    grid.sync();

    if (blk == 0 && tid == 0) {
        float A2 = p.acc[0], A3 = p.acc[1];
        float t1 = 1.f/81.f;
        float t2 = (2.f/(NS*16.f)) * (A2 / NB);
        float t3 = (A3 / ((float)NS*(float)NS)) / NB;
        p.out[0] = t1 - t2 + t3;
    }
}

extern "C" void kernel_launch(void* const* d_in, const int* in_sizes, int n_in,
                              void* d_out, int out_size, void* d_ws, size_t ws_size,
                              hipStream_t stream)
{
    Pm pm;
    pm.x    = (const float*)d_in[0];
    const int* ei = (const int*)d_in[1];
    pm.srcv = ei; pm.tgtv = ei + NE;
    pm.encW = (const float*)d_in[2];  pm.encB = (const float*)d_in[3];
    pm.m1w  = (const float*)d_in[4];  pm.m1b  = (const float*)d_in[5];
    pm.m2w  = (const float*)d_in[6];  pm.m2b  = (const float*)d_in[7];
    pm.u1w  = (const float*)d_in[8];  pm.u1b  = (const float*)d_in[9];
    pm.u2w  = (const float*)d_in[10]; pm.u2b  = (const float*)d_in[11];
    pm.dw   = (const float*)d_in[12]; pm.db   = (const float*)d_in[13];
    pm.out  = (float*)d_out;

    float* w = (float*)d_ws;
    pm.h   = w;              // NN*64
    pm.agg = pm.h  + NN*64;  // NN*64
    pm.A   = pm.agg + NN*64; // NN*64 (also xbuf after last edge)
    pm.Bm  = pm.A  + NN*64;  // NN*64
    pm.g0  = pm.Bm + NN*64;  // 2*NB*64
    pm.g1  = pm.g0 + 2*NB*64;
    pm.acc = pm.g1 + 2*NB*64; // 4
    pm.deg  = (int*)(pm.acc + 4);   // NN
    pm.ssrc = pm.deg + NN;          // NN*64

    int nb = 0;
    hipOccupancyMaxActiveBlocksPerMultiprocessor(&nb, k_mega, 256, 0);
    if (nb < 1) nb = 2;
    int grid = nb * 256;
    if (grid > 768) grid = 768;

    void* args[] = { (void*)&pm };
    hipLaunchCooperativeKernel((const void*)k_mega, dim3(grid), dim3(256),
                               args, 0, stream);
}

// Round 8
// 240.953 us; speedup vs baseline: 2.5752x; 2.5752x over previous
//
#include <hip/hip_runtime.h>
#include <hip/hip_fp16.h>
#include <math.h>

#define NB 8
#define NS 2048
#define NN (NB*NS)       // 16384 nodes
#define NE (NN*16)       // 262144 edges
#define EPSF 1e-5f

typedef float  f32x4 __attribute__((ext_vector_type(4)));
typedef _Float16 f16x8 __attribute__((ext_vector_type(8)));
union F8 { f16x8 v; unsigned u[4]; };

__device__ __forceinline__ unsigned pk2h(float a, float b) {
    __half2 hh = __floats2half2_rn(a, b);
    unsigned u; __builtin_memcpy(&u, &hh, 4); return u;
}

// zero deg (NN) and acc (4)
__global__ __launch_bounds__(256) void k_init(int* __restrict__ deg,
                                              float* __restrict__ acc)
{
    int i = blockIdx.x*256 + threadIdx.x;
    if (i < NN) deg[i] = 0;
    if (i < 4) acc[i] = 0.f;
}

// Layer 0 (MFMA): slotted-CSR scatter; enc -> h; A = h@W1a+b1; Bm = h@W1b; zero g0.
__global__ __launch_bounds__(256) void k_pre0M(
    const float* __restrict__ x,
    const float* __restrict__ encW, const float* __restrict__ encB,
    float* __restrict__ h,
    const float* __restrict__ W1, const float* __restrict__ B1,
    float* __restrict__ A, float* __restrict__ Bm,
    float* __restrict__ gz,
    const int* __restrict__ srcv, const int* __restrict__ tgtv,
    int* __restrict__ deg, int* __restrict__ ssrc)
{
    alignas(16) __shared__ _Float16 sWp[8192];   // [ks2][nt8][qd4][col16][j8]
    __shared__ float sEw[256], sEb[64];
    {   // slotted-CSR scatter: 4 edges per thread (256 blocks x 256 thr)
        int gid = blockIdx.x*256 + threadIdx.x;
        #pragma unroll
        for (int it = 0; it < 4; it++) {
            int e = gid + it*65536;
            int t = tgtv[e];
            int pos = atomicAdd(&deg[t], 1) & 63;
            ssrc[t*64 + pos] = srcv[e];
        }
    }
    for (int idx = threadIdx.x; idx < 8192; idx += 256) {
        int k = idx >> 7, n = idx & 127;
        float val = (n < 64) ? W1[k*64 + n] : W1[(64+k)*64 + (n-64)];
        int ks = k >> 5, qd = (k >> 3) & 3, j = k & 7, nt = n >> 4, cl = n & 15;
        sWp[(((ks*8+nt)*4+qd)*16+cl)*8 + j] = (_Float16)val;
    }
    sEw[threadIdx.x] = encW[threadIdx.x];
    if (threadIdx.x < 64) sEb[threadIdx.x] = encB[threadIdx.x];
    if (blockIdx.x == 0)
        for (int i = threadIdx.x; i < 2*NB*64; i += 256) gz[i] = 0.f;
    __syncthreads();
    const int lane = threadIdx.x & 63;
    const int wv = threadIdx.x >> 6;
    const int col = lane & 15, quad = lane >> 4;
    const int n0w = blockIdx.x*64 + wv*16;
    const int n = n0w + col;
    float4 x4 = *(const float4*)&x[(size_t)n*4];
    float xv[16];
    #pragma unroll
    for (int hh = 0; hh < 2; hh++)
        #pragma unroll
        for (int j = 0; j < 8; j++) {
            int f = hh*32 + quad*8 + j;
            float v = sEb[f];
            v = fmaf(x4.x, sEw[f],     v);
            v = fmaf(x4.y, sEw[64+f],  v);
            v = fmaf(x4.z, sEw[128+f], v);
            v = fmaf(x4.w, sEw[192+f], v);
            xv[hh*8+j] = v;
        }
    float* hp = &h[(size_t)n*64 + quad*8];
    *(float4*)&hp[0]  = *(float4*)&xv[0];
    *(float4*)&hp[4]  = *(float4*)&xv[4];
    *(float4*)&hp[32] = *(float4*)&xv[8];
    *(float4*)&hp[36] = *(float4*)&xv[12];
    F8 af0, af1;
    af0.u[0] = pk2h(xv[0],  xv[1]);  af0.u[1] = pk2h(xv[2],  xv[3]);
    af0.u[2] = pk2h(xv[4],  xv[5]);  af0.u[3] = pk2h(xv[6],  xv[7]);
    af1.u[0] = pk2h(xv[8],  xv[9]);  af1.u[1] = pk2h(xv[10], xv[11]);
    af1.u[2] = pk2h(xv[12], xv[13]); af1.u[3] = pk2h(xv[14], xv[15]);
    float b1v[4];
    #pragma unroll
    for (int nt = 0; nt < 4; nt++) b1v[nt] = B1[nt*16+col];
    #pragma unroll
    for (int nt = 0; nt < 8; nt++) {
        f32x4 acc = {0.f,0.f,0.f,0.f};
        F8 bf; bf.v = *(const f16x8*)&sWp[(((0*8+nt)*4+quad)*16+col)*8];
        acc = __builtin_amdgcn_mfma_f32_16x16x32_f16(af0.v, bf.v, acc, 0, 0, 0);
        bf.v = *(const f16x8*)&sWp[(((1*8+nt)*4+quad)*16+col)*8];
        acc = __builtin_amdgcn_mfma_f32_16x16x32_f16(af1.v, bf.v, acc, 0, 0, 0);
        if (nt < 4) {
            float bb = b1v[nt];
            A[(size_t)(n0w + quad*4 + 0)*64 + nt*16 + col] = acc.x + bb;
            A[(size_t)(n0w + quad*4 + 1)*64 + nt*16 + col] = acc.y + bb;
            A[(size_t)(n0w + quad*4 + 2)*64 + nt*16 + col] = acc.z + bb;
            A[(size_t)(n0w + quad*4 + 3)*64 + nt*16 + col] = acc.w + bb;
        } else {
            Bm[(size_t)(n0w + quad*4 + 0)*64 + (nt-4)*16 + col] = acc.x;
            Bm[(size_t)(n0w + quad*4 + 1)*64 + (nt-4)*16 + col] = acc.y;
            Bm[(size_t)(n0w + quad*4 + 2)*64 + (nt-4)*16 + col] = acc.z;
            Bm[(size_t)(n0w + quad*4 + 3)*64 + (nt-4)*16 + col] = acc.w;
        }
    }
}

// Slotted-CSR edge kernel: one wave per target, register-direct fragments, plain stores.
__global__ __launch_bounds__(256) void k_edge4(
    const float* __restrict__ A, const float* __restrict__ Bm,
    const int* __restrict__ deg, const int* __restrict__ ssrc,
    const float* __restrict__ W2, const float* __restrict__ B2,
    float* __restrict__ agg)
{
    __shared__ float sW[64*64];
    for (int i = threadIdx.x; i < 64*64; i += 256) sW[i] = W2[i];
    __syncthreads();
    const int lane = threadIdx.x & 63;
    const int col = lane & 15, quad = lane >> 4;
    F8 bf[4][2];
    #pragma unroll
    for (int nt = 0; nt < 4; nt++)
        #pragma unroll
        for (int ks = 0; ks < 2; ks++)
            #pragma unroll
            for (int jj = 0; jj < 4; jj++) {
                int k = ks*32 + quad*8 + jj*2;
                bf[nt][ks].u[jj] = pk2h(sW[k*64 + nt*16 + col],
                                        sW[(k+1)*64 + nt*16 + col]);
            }
    float b2v[4];
    #pragma unroll
    for (int nt = 0; nt < 4; nt++) b2v[nt] = B2[nt*16 + col];

    const int wid = blockIdx.x*4 + (threadIdx.x >> 6);
    const int nwv = gridDim.x*4;
    for (int t = wid; t < NN; t += nwv) {
        int cnt = deg[t]; if (cnt > 64) cnt = 64;
        int base = t*64;
        const float* ar = &A[(size_t)t*64 + quad*8];
        float4 a0 = *(const float4*)&ar[0];
        float4 a1 = *(const float4*)&ar[4];
        float4 a2 = *(const float4*)&ar[32];
        float4 a3 = *(const float4*)&ar[36];
        float cs[4] = {0.f, 0.f, 0.f, 0.f};
        for (int s0 = 0; s0 < cnt; s0 += 16) {
            int v = cnt - s0;
            int cc = col < v-1 ? col : v-1;
            int sr = ssrc[base + s0 + cc];
            const float* br = &Bm[(size_t)sr*64 + quad*8];
            float4 b0 = *(const float4*)&br[0];
            float4 b1 = *(const float4*)&br[4];
            float4 b2_ = *(const float4*)&br[32];
            float4 b3 = *(const float4*)&br[36];
            F8 af0, af1;
            af0.u[0] = pk2h(fmaxf(a0.x+b0.x,0.f), fmaxf(a0.y+b0.y,0.f));
            af0.u[1] = pk2h(fmaxf(a0.z+b0.z,0.f), fmaxf(a0.w+b0.w,0.f));
            af0.u[2] = pk2h(fmaxf(a1.x+b1.x,0.f), fmaxf(a1.y+b1.y,0.f));
            af0.u[3] = pk2h(fmaxf(a1.z+b1.z,0.f), fmaxf(a1.w+b1.w,0.f));
            af1.u[0] = pk2h(fmaxf(a2.x+b2_.x,0.f), fmaxf(a2.y+b2_.y,0.f));
            af1.u[1] = pk2h(fmaxf(a2.z+b2_.z,0.f), fmaxf(a2.w+b2_.w,0.f));
            af1.u[2] = pk2h(fmaxf(a3.x+b3.x,0.f), fmaxf(a3.y+b3.y,0.f));
            af1.u[3] = pk2h(fmaxf(a3.z+b3.z,0.f), fmaxf(a3.w+b3.w,0.f));
            #pragma unroll
            for (int nt = 0; nt < 4; nt++) {
                f32x4 acc = __builtin_amdgcn_mfma_f32_16x16x32_f16(
                                af0.v, bf[nt][0].v, (f32x4){0.f,0.f,0.f,0.f}, 0, 0, 0);
                acc = __builtin_amdgcn_mfma_f32_16x16x32_f16(
                                af1.v, bf[nt][1].v, acc, 0, 0, 0);
                float r0 = (quad*4+0 < v) ? fmaxf(acc.x + b2v[nt], 0.f) : 0.f;
                float r1 = (quad*4+1 < v) ? fmaxf(acc.y + b2v[nt], 0.f) : 0.f;
                float r2 = (quad*4+2 < v) ? fmaxf(acc.z + b2v[nt], 0.f) : 0.f;
                float r3 = (quad*4+3 < v) ? fmaxf(acc.w + b2v[nt], 0.f) : 0.f;
                cs[nt] += (r0 + r1) + (r2 + r3);
            }
        }
        #pragma unroll
        for (int nt = 0; nt < 4; nt++) {
            float vv = cs[nt];
            vv += __shfl_down(vv, 32, 64);
            vv += __shfl_down(vv, 16, 64);
            cs[nt] = vv;
        }
        if (lane < 16) {
            agg[(size_t)t*64 +  0 + lane] = cs[0];
            agg[(size_t)t*64 + 16 + lane] = cs[1];
            agg[(size_t)t*64 + 32 + lane] = cs[2];
            agg[(size_t)t*64 + 48 + lane] = cs[3];
        }
    }
}

// MFMA update MLP: h <- relu(W2^T relu(W1^T [h;agg] + b1) + b2); stats -> gout.
__global__ __launch_bounds__(256) void k_updateM(
    float* __restrict__ h, const float* __restrict__ agg,
    const float* __restrict__ W1, const float* __restrict__ B1,
    const float* __restrict__ W2, const float* __restrict__ B2,
    float* __restrict__ gout)
{
    alignas(16) __shared__ _Float16 sW1u[8192];   // [ks4][nt4][qd4][col16][j8]
    alignas(16) __shared__ _Float16 sW2u[4096];   // [ks2][nt4][qd4][col16][j8]
    alignas(16) __shared__ float sHid[4][16*68];
    __shared__ float sSum[4][64], sSq[4][64];
    for (int idx = threadIdx.x; idx < 8192; idx += 256) {
        int k = idx >> 6, n = idx & 63;
        int ks = k >> 5, qd = (k >> 3) & 3, j = k & 7, nt = n >> 4, cl = n & 15;
        sW1u[(((ks*4+nt)*4+qd)*16+cl)*8 + j] = (_Float16)W1[idx];
    }
    for (int idx = threadIdx.x; idx < 4096; idx += 256) {
        int k = idx >> 6, n = idx & 63;
        int ks = k >> 5, qd = (k >> 3) & 3, j = k & 7, nt = n >> 4, cl = n & 15;
        sW2u[(((ks*4+nt)*4+qd)*16+cl)*8 + j] = (_Float16)W2[idx];
    }
    __syncthreads();
    const int lane = threadIdx.x & 63;
    const int wv = threadIdx.x >> 6;
    const int col = lane & 15, quad = lane >> 4;
    const int n0w = blockIdx.x*64 + wv*16;
    const float* hp = &h[(size_t)(n0w+col)*64 + quad*8];
    const float* ap = &agg[(size_t)(n0w+col)*64 + quad*8];
    float4 h0 = *(const float4*)&hp[0];
    float4 h1 = *(const float4*)&hp[4];
    float4 h2 = *(const float4*)&hp[32];
    float4 h3 = *(const float4*)&hp[36];
    float4 g0 = *(const float4*)&ap[0];
    float4 g1 = *(const float4*)&ap[4];
    float4 g2 = *(const float4*)&ap[32];
    float4 g3 = *(const float4*)&ap[36];
    F8 af[4];
    af[0].u[0] = pk2h(h0.x, h0.y); af[0].u[1] = pk2h(h0.z, h0.w);
    af[0].u[2] = pk2h(h1.x, h1.y); af[0].u[3] = pk2h(h1.z, h1.w);
    af[1].u[0] = pk2h(h2.x, h2.y); af[1].u[1] = pk2h(h2.z, h2.w);
    af[1].u[2] = pk2h(h3.x, h3.y); af[1].u[3] = pk2h(h3.z, h3.w);
    af[2].u[0] = pk2h(g0.x, g0.y); af[2].u[1] = pk2h(g0.z, g0.w);
    af[2].u[2] = pk2h(g1.x, g1.y); af[2].u[3] = pk2h(g1.z, g1.w);
    af[3].u[0] = pk2h(g2.x, g2.y); af[3].u[1] = pk2h(g2.z, g2.w);
    af[3].u[2] = pk2h(g3.x, g3.y); af[3].u[3] = pk2h(g3.z, g3.w);
    float b1v[4], b2v[4];
    #pragma unroll
    for (int nt = 0; nt < 4; nt++) { b1v[nt] = B1[nt*16+col]; b2v[nt] = B2[nt*16+col]; }
    float* hid = &sHid[wv][0];
    #pragma unroll
    for (int nt = 0; nt < 4; nt++) {
        f32x4 acc = {0.f,0.f,0.f,0.f};
        #pragma unroll
        for (int ks = 0; ks < 4; ks++) {
            F8 bf; bf.v = *(const f16x8*)&sW1u[(((ks*4+nt)*4+quad)*16+col)*8];
            acc = __builtin_amdgcn_mfma_f32_16x16x32_f16(af[ks].v, bf.v, acc, 0, 0, 0);
        }
        hid[(quad*4+0)*68 + nt*16+col] = fmaxf(acc.x + b1v[nt], 0.f);
        hid[(quad*4+1)*68 + nt*16+col] = fmaxf(acc.y + b1v[nt], 0.f);
        hid[(quad*4+2)*68 + nt*16+col] = fmaxf(acc.z + b1v[nt], 0.f);
        hid[(quad*4+3)*68 + nt*16+col] = fmaxf(acc.w + b1v[nt], 0.f);
    }
    __syncthreads();
    const float* hr = &hid[col*68 + quad*8];
    float4 q0 = *(const float4*)&hr[0];
    float4 q1 = *(const float4*)&hr[4];
    float4 q2 = *(const float4*)&hr[32];
    float4 q3 = *(const float4*)&hr[36];
    F8 e0, e1;
    e0.u[0] = pk2h(q0.x, q0.y); e0.u[1] = pk2h(q0.z, q0.w);
    e0.u[2] = pk2h(q1.x, q1.y); e0.u[3] = pk2h(q1.z, q1.w);
    e1.u[0] = pk2h(q2.x, q2.y); e1.u[1] = pk2h(q2.z, q2.w);
    e1.u[2] = pk2h(q3.x, q3.y); e1.u[3] = pk2h(q3.z, q3.w);
    float ss[4], sq[4];
    #pragma unroll
    for (int nt = 0; nt < 4; nt++) {
        f32x4 acc = {0.f,0.f,0.f,0.f};
        F8 bf; bf.v = *(const f16x8*)&sW2u[(((0*4+nt)*4+quad)*16+col)*8];
        acc = __builtin_amdgcn_mfma_f32_16x16x32_f16(e0.v, bf.v, acc, 0, 0, 0);
        bf.v = *(const f16x8*)&sW2u[(((1*4+nt)*4+quad)*16+col)*8];
        acc = __builtin_amdgcn_mfma_f32_16x16x32_f16(e1.v, bf.v, acc, 0, 0, 0);
        float o0 = fmaxf(acc.x + b2v[nt], 0.f);
        float o1 = fmaxf(acc.y + b2v[nt], 0.f);
        float o2 = fmaxf(acc.z + b2v[nt], 0.f);
        float o3 = fmaxf(acc.w + b2v[nt], 0.f);
        h[(size_t)(n0w + quad*4 + 0)*64 + nt*16 + col] = o0;
        h[(size_t)(n0w + quad*4 + 1)*64 + nt*16 + col] = o1;
        h[(size_t)(n0w + quad*4 + 2)*64 + nt*16 + col] = o2;
        h[(size_t)(n0w + quad*4 + 3)*64 + nt*16 + col] = o3;
        ss[nt] = (o0 + o1) + (o2 + o3);
        sq[nt] = (o0*o0 + o1*o1) + (o2*o2 + o3*o3);
    }
    #pragma unroll
    for (int nt = 0; nt < 4; nt++) {
        float v = ss[nt];
        v += __shfl_down(v, 32, 64); v += __shfl_down(v, 16, 64);
        float w2 = sq[nt];
        w2 += __shfl_down(w2, 32, 64); w2 += __shfl_down(w2, 16, 64);
        if (lane < 16) { sSum[wv][nt*16+lane] = v; sSq[wv][nt*16+lane] = w2; }
    }
    __syncthreads();
    if (threadIdx.x < 128) {
        int ch = threadIdx.x & 63, hf = threadIdx.x >> 6;
        int b = (int)(blockIdx.x >> 5);
        if (hf == 0) {
            float t_ = sSum[0][ch]+sSum[1][ch]+sSum[2][ch]+sSum[3][ch];
            atomicAdd(&gout[b*64 + ch], t_);
        } else {
            float t_ = sSq[0][ch]+sSq[1][ch]+sSq[2][ch]+sSq[3][ch];
            atomicAdd(&gout[NB*64 + b*64 + ch], t_);
        }
    }
}

// MFMA pre (layers 1,2): normalize h (write back), A = h@W1a+b1, B = h@W1b; zero gz.
__global__ __launch_bounds__(256) void k_preM(
    float* __restrict__ h,
    const float* __restrict__ W1, const float* __restrict__ B1,
    float* __restrict__ A, float* __restrict__ Bm,
    const float* __restrict__ gin, float* __restrict__ gz)
{
    alignas(16) __shared__ _Float16 sWp[8192];   // [ks2][nt8][qd4][col16][j8]
    __shared__ float sMean[64], sRstd[64];
    for (int idx = threadIdx.x; idx < 8192; idx += 256) {
        int k = idx >> 7, n = idx & 127;
        float val = (n < 64) ? W1[k*64 + n] : W1[(64+k)*64 + (n-64)];
        int ks = k >> 5, qd = (k >> 3) & 3, j = k & 7, nt = n >> 4, cl = n & 15;
        sWp[(((ks*8+nt)*4+qd)*16+cl)*8 + j] = (_Float16)val;
    }
    if (threadIdx.x < 64) {
        int b = (int)(blockIdx.x >> 5);
        float s  = gin[b*64 + threadIdx.x];
        float qq = gin[NB*64 + b*64 + threadIdx.x];
        float mean = s * (1.f/NS);
        float var  = qq * (1.f/NS) - mean*mean;
        sMean[threadIdx.x] = mean;
        sRstd[threadIdx.x] = rsqrtf(var + EPSF);
    }
    if (blockIdx.x == 0)
        for (int i = threadIdx.x; i < 2*NB*64; i += 256) gz[i] = 0.f;
    __syncthreads();
    const int lane = threadIdx.x & 63;
    const int wv = threadIdx.x >> 6;
    const int col = lane & 15, quad = lane >> 4;
    const int n0w = blockIdx.x*64 + wv*16;
    float* hp = &h[(size_t)(n0w+col)*64 + quad*8];
    float xv[16];
    *(float4*)&xv[0]  = *(const float4*)&hp[0];
    *(float4*)&xv[4]  = *(const float4*)&hp[4];
    *(float4*)&xv[8]  = *(const float4*)&hp[32];
    *(float4*)&xv[12] = *(const float4*)&hp[36];
    #pragma unroll
    for (int t2 = 0; t2 < 8; t2++) {
        int f = quad*8 + t2;
        xv[t2] = (xv[t2] - sMean[f]) * sRstd[f];
    }
    #pragma unroll
    for (int t2 = 0; t2 < 8; t2++) {
        int f = 32 + quad*8 + t2;
        xv[8+t2] = (xv[8+t2] - sMean[f]) * sRstd[f];
    }
    *(float4*)&hp[0]  = *(float4*)&xv[0];
    *(float4*)&hp[4]  = *(float4*)&xv[4];
    *(float4*)&hp[32] = *(float4*)&xv[8];
    *(float4*)&hp[36] = *(float4*)&xv[12];
    F8 af0, af1;
    af0.u[0] = pk2h(xv[0],  xv[1]);  af0.u[1] = pk2h(xv[2],  xv[3]);
    af0.u[2] = pk2h(xv[4],  xv[5]);  af0.u[3] = pk2h(xv[6],  xv[7]);
    af1.u[0] = pk2h(xv[8],  xv[9]);  af1.u[1] = pk2h(xv[10], xv[11]);
    af1.u[2] = pk2h(xv[12], xv[13]); af1.u[3] = pk2h(xv[14], xv[15]);
    float b1v[4];
    #pragma unroll
    for (int nt = 0; nt < 4; nt++) b1v[nt] = B1[nt*16+col];
    #pragma unroll
    for (int nt = 0; nt < 8; nt++) {
        f32x4 acc = {0.f,0.f,0.f,0.f};
        F8 bf; bf.v = *(const f16x8*)&sWp[(((0*8+nt)*4+quad)*16+col)*8];
        acc = __builtin_amdgcn_mfma_f32_16x16x32_f16(af0.v, bf.v, acc, 0, 0, 0);
        bf.v = *(const f16x8*)&sWp[(((1*8+nt)*4+quad)*16+col)*8];
        acc = __builtin_amdgcn_mfma_f32_16x16x32_f16(af1.v, bf.v, acc, 0, 0, 0);
        if (nt < 4) {
            float bb = b1v[nt];
            A[(size_t)(n0w + quad*4 + 0)*64 + nt*16 + col] = acc.x + bb;
            A[(size_t)(n0w + quad*4 + 1)*64 + nt*16 + col] = acc.y + bb;
            A[(size_t)(n0w + quad*4 + 2)*64 + nt*16 + col] = acc.z + bb;
            A[(size_t)(n0w + quad*4 + 3)*64 + nt*16 + col] = acc.w + bb;
        } else {
            Bm[(size_t)(n0w + quad*4 + 0)*64 + (nt-4)*16 + col] = acc.x;
            Bm[(size_t)(n0w + quad*4 + 1)*64 + (nt-4)*16 + col] = acc.y;
            Bm[(size_t)(n0w + quad*4 + 2)*64 + (nt-4)*16 + col] = acc.z;
            Bm[(size_t)(n0w + quad*4 + 3)*64 + (nt-4)*16 + col] = acc.w;
        }
    }
}

// Fused: instance-norm + decode + sigmoid + t2-term reduction
__global__ __launch_bounds__(256) void k_dec(
    const float* __restrict__ h, const float* __restrict__ Wd, const float* __restrict__ bd,
    const float* __restrict__ g, float* __restrict__ xbuf, float* __restrict__ out1,
    float* __restrict__ accum)
{
    int n = blockIdx.x*256 + threadIdx.x;
    int b = n >> 11;
    __shared__ float sM[64], sR[64];
    __shared__ float sWd[256];
    if (threadIdx.x < 64) {
        float s  = g[b*64 + threadIdx.x];
        float qq = g[NB*64 + b*64 + threadIdx.x];
        float mean = s * (1.f/NS);
        float var  = qq * (1.f/NS) - mean*mean;
        sM[threadIdx.x] = mean; sR[threadIdx.x] = rsqrtf(var + EPSF);
    }
    for (int i = threadIdx.x; i < 256; i += 256) sWd[i] = Wd[i];
    __syncthreads();
    float a0 = bd[0], a1 = bd[1], a2 = bd[2], a3 = bd[3];
    const float* hr = h + (size_t)n*64;
    #pragma unroll 8
    for (int k = 0; k < 64; k++) {
        float v = (hr[k] - sM[k]) * sR[k];
        a0 = fmaf(v, sWd[k*4+0], a0);
        a1 = fmaf(v, sWd[k*4+1], a1);
        a2 = fmaf(v, sWd[k*4+2], a2);
        a3 = fmaf(v, sWd[k*4+3], a3);
    }
    float4 o;
    o.x = 1.f/(1.f + expf(-a0));
    o.y = 1.f/(1.f + expf(-a1));
    o.z = 1.f/(1.f + expf(-a2));
    o.w = 1.f/(1.f + expf(-a3));
    *(float4*)&xbuf[(size_t)n*4] = o;
    out1[n*4+0] = o.x; out1[n*4+1] = o.y; out1[n*4+2] = o.z; out1[n*4+3] = o.w;
    float p = (1.f-o.x*o.x)*(1.f-o.y*o.y)*(1.f-o.z*o.z)*(1.f-o.w*o.w);
    for (int offs = 32; offs; offs >>= 1) p += __shfl_down(p, offs, 64);
    __shared__ float ws[4];
    if ((threadIdx.x & 63) == 0) ws[threadIdx.x >> 6] = p;
    __syncthreads();
    if (threadIdx.x == 0) atomicAdd(&accum[0], ws[0]+ws[1]+ws[2]+ws[3]);
}

// t3 pairwise term + final loss via last-block ticket
__global__ __launch_bounds__(256) void k_t3(const float* __restrict__ X,
                                            float* __restrict__ accum,
                                            float* __restrict__ out)
{
    int b = blockIdx.x >> 5, c = blockIdx.x & 31;
    __shared__ float sX[NS*4];
    const float* Xb = X + (size_t)b*NS*4;
    for (int idx = threadIdx.x; idx < NS*4; idx += 256) sX[idx] = Xb[idx];
    __syncthreads();
    const float4* sX4 = (const float4*)sX;
    int il = threadIdx.x & 63, wv = threadIdx.x >> 6;
    float4 xi = sX4[c*64 + il];
    float acc = 0.f;
    #pragma unroll 4
    for (int s = 0; s < 512; s++) {
        float4 xj = sX4[wv*512 + s];
        acc += (1.f - fmaxf(xi.x, xj.x)) * (1.f - fmaxf(xi.y, xj.y))
             * (1.f - fmaxf(xi.z, xj.z)) * (1.f - fmaxf(xi.w, xj.w));
    }
    for (int offs = 32; offs; offs >>= 1) acc += __shfl_down(acc, offs, 64);
    __shared__ float ws[4];
    if (il == 0) ws[wv] = acc;
    __syncthreads();
    if (threadIdx.x == 0) {
        atomicAdd(&accum[1], ws[0]+ws[1]+ws[2]+ws[3]);
        __threadfence();
        unsigned t = atomicAdd((unsigned int*)&accum[2], 1u);
        if (t == (unsigned)(NB*32 - 1)) {
            float A2 = __hip_atomic_load(&accum[0], __ATOMIC_ACQUIRE, __HIP_MEMORY_SCOPE_AGENT);
            float A3 = __hip_atomic_load(&accum[1], __ATOMIC_ACQUIRE, __HIP_MEMORY_SCOPE_AGENT);
            float t1 = 1.f/81.f;
            float t2 = (2.f/(NS*16.f)) * (A2 / NB);
            float t3 = (A3 / ((float)NS*(float)NS)) / NB;
            out[0] = t1 - t2 + t3;
        }
    }
}

extern "C" void kernel_launch(void* const* d_in, const int* in_sizes, int n_in,
                              void* d_out, int out_size, void* d_ws, size_t ws_size,
                              hipStream_t stream)
{
    const float* x     = (const float*)d_in[0];
    const int*   ei    = (const int*)d_in[1];
    const float* enc_w = (const float*)d_in[2];
    const float* enc_b = (const float*)d_in[3];
    const float* m1w   = (const float*)d_in[4];
    const float* m1b   = (const float*)d_in[5];
    const float* m2w   = (const float*)d_in[6];
    const float* m2b   = (const float*)d_in[7];
    const float* u1w   = (const float*)d_in[8];
    const float* u1b   = (const float*)d_in[9];
    const float* u2w   = (const float*)d_in[10];
    const float* u2b   = (const float*)d_in[11];
    const float* dw    = (const float*)d_in[12];
    const float* db    = (const float*)d_in[13];
    float* out = (float*)d_out;

    float* h    = (float*)d_ws;            // NN*64
    float* agg  = h    + NN*64;            // NN*64
    float* Apre = agg  + NN*64;            // NN*64
    float* Bpre = Apre + NN*64;            // NN*64
    float* g0   = Bpre + NN*64;            // 2*NB*64
    float* g1   = g0   + 2*NB*64;          // 2*NB*64
    float* acc  = g1   + 2*NB*64;          // 4
    int*   deg  = (int*)(acc + 4);         // NN
    int*   ssrc = deg + NN;                // NN*64
    float* xbuf = Apre;                    // alias (Apre dead after last edge)

    const int* srcv = ei;
    const int* tgtv = ei + NE;
    float* gbuf[2] = {g0, g1};

    k_init<<<NN/256, 256, 0, stream>>>(deg, acc);
    k_pre0M<<<NN/64, 256, 0, stream>>>(x, enc_w, enc_b, h, m1w, m1b,
                                       Apre, Bpre, g0, srcv, tgtv, deg, ssrc);

    for (int l = 0; l < 3; l++) {
        if (l)
            k_preM<<<NN/64, 256, 0, stream>>>(h, m1w + l*128*64, m1b + l*64,
                                              Apre, Bpre,
                                              gbuf[(l+1)&1], gbuf[l&1]);
        k_edge4<<<1024, 256, 0, stream>>>(Apre, Bpre, deg, ssrc,
                                          m2w + l*64*64, m2b + l*64, agg);
        k_updateM<<<NN/64, 256, 0, stream>>>(h, agg,
                                             u1w + l*128*64, u1b + l*64,
                                             u2w + l*64*64,  u2b + l*64,
                                             gbuf[l&1]);
    }

    k_dec<<<NN/256, 256, 0, stream>>>(h, dw, db, g0, xbuf, out + 1, acc);
    k_t3<<<NB*32, 256, 0, stream>>>(xbuf, acc, out);
}

// Round 9
// 229.639 us; speedup vs baseline: 2.7020x; 1.0493x over previous
//
#include <hip/hip_runtime.h>
#include <hip/hip_fp16.h>
#include <math.h>

#define NB 8
#define NS 2048
#define NN (NB*NS)       // 16384 nodes
#define NE (NN*16)       // 262144 edges
#define EPSF 1e-5f

typedef float  f32x4 __attribute__((ext_vector_type(4)));
typedef _Float16 f16x8 __attribute__((ext_vector_type(8)));
union F8 { f16x8 v; unsigned u[4]; };

__device__ __forceinline__ unsigned pk2h(float a, float b) {
    __half2 hh = __floats2half2_rn(a, b);
    unsigned u; __builtin_memcpy(&u, &hh, 4); return u;
}

// zero deg (NN) and acc (4)
__global__ __launch_bounds__(256) void k_init(int* __restrict__ deg,
                                              float* __restrict__ acc)
{
    int i = blockIdx.x*256 + threadIdx.x;
    if (i < NN) deg[i] = 0;
    if (i < 4) acc[i] = 0.f;
}

// Layer 0 (MFMA): slotted-CSR scatter; enc -> h; A = h@W1a+b1; Bm = h@W1b; zero g0.
__global__ __launch_bounds__(256) void k_pre0M(
    const float* __restrict__ x,
    const float* __restrict__ encW, const float* __restrict__ encB,
    float* __restrict__ h,
    const float* __restrict__ W1, const float* __restrict__ B1,
    float* __restrict__ A, float* __restrict__ Bm,
    float* __restrict__ gz,
    const int* __restrict__ srcv, const int* __restrict__ tgtv,
    int* __restrict__ deg, int* __restrict__ ssrc)
{
    alignas(16) __shared__ _Float16 sWp[8192];   // [ks2][nt8][qd4][col16][j8]
    __shared__ float sEw[256], sEb[64];
    {   // slotted-CSR scatter: 4 edges per thread (256 blocks x 256 thr)
        int gid = blockIdx.x*256 + threadIdx.x;
        #pragma unroll
        for (int it = 0; it < 4; it++) {
            int e = gid + it*65536;
            int t = tgtv[e];
            int pos = atomicAdd(&deg[t], 1) & 63;
            ssrc[t*64 + pos] = srcv[e];
        }
    }
    for (int idx = threadIdx.x; idx < 8192; idx += 256) {
        int k = idx >> 7, n = idx & 127;
        float val = (n < 64) ? W1[k*64 + n] : W1[(64+k)*64 + (n-64)];
        int ks = k >> 5, qd = (k >> 3) & 3, j = k & 7, nt = n >> 4, cl = n & 15;
        sWp[(((ks*8+nt)*4+qd)*16+cl)*8 + j] = (_Float16)val;
    }
    sEw[threadIdx.x] = encW[threadIdx.x];
    if (threadIdx.x < 64) sEb[threadIdx.x] = encB[threadIdx.x];
    if (blockIdx.x == 0)
        for (int i = threadIdx.x; i < 2*NB*64; i += 256) gz[i] = 0.f;
    __syncthreads();
    const int lane = threadIdx.x & 63;
    const int wv = threadIdx.x >> 6;
    const int col = lane & 15, quad = lane >> 4;
    const int n0w = blockIdx.x*64 + wv*16;
    const int n = n0w + col;
    float4 x4 = *(const float4*)&x[(size_t)n*4];
    float xv[16];
    #pragma unroll
    for (int hh = 0; hh < 2; hh++)
        #pragma unroll
        for (int j = 0; j < 8; j++) {
            int f = hh*32 + quad*8 + j;
            float v = sEb[f];
            v = fmaf(x4.x, sEw[f],     v);
            v = fmaf(x4.y, sEw[64+f],  v);
            v = fmaf(x4.z, sEw[128+f], v);
            v = fmaf(x4.w, sEw[192+f], v);
            xv[hh*8+j] = v;
        }
    float* hp = &h[(size_t)n*64 + quad*8];
    *(float4*)&hp[0]  = *(float4*)&xv[0];
    *(float4*)&hp[4]  = *(float4*)&xv[4];
    *(float4*)&hp[32] = *(float4*)&xv[8];
    *(float4*)&hp[36] = *(float4*)&xv[12];
    F8 af0, af1;
    af0.u[0] = pk2h(xv[0],  xv[1]);  af0.u[1] = pk2h(xv[2],  xv[3]);
    af0.u[2] = pk2h(xv[4],  xv[5]);  af0.u[3] = pk2h(xv[6],  xv[7]);
    af1.u[0] = pk2h(xv[8],  xv[9]);  af1.u[1] = pk2h(xv[10], xv[11]);
    af1.u[2] = pk2h(xv[12], xv[13]); af1.u[3] = pk2h(xv[14], xv[15]);
    float b1v[4];
    #pragma unroll
    for (int nt = 0; nt < 4; nt++) b1v[nt] = B1[nt*16+col];
    #pragma unroll
    for (int nt = 0; nt < 8; nt++) {
        f32x4 acc = {0.f,0.f,0.f,0.f};
        F8 bf; bf.v = *(const f16x8*)&sWp[(((0*8+nt)*4+quad)*16+col)*8];
        acc = __builtin_amdgcn_mfma_f32_16x16x32_f16(af0.v, bf.v, acc, 0, 0, 0);
        bf.v = *(const f16x8*)&sWp[(((1*8+nt)*4+quad)*16+col)*8];
        acc = __builtin_amdgcn_mfma_f32_16x16x32_f16(af1.v, bf.v, acc, 0, 0, 0);
        if (nt < 4) {
            float bb = b1v[nt];
            A[(size_t)(n0w + quad*4 + 0)*64 + nt*16 + col] = acc.x + bb;
            A[(size_t)(n0w + quad*4 + 1)*64 + nt*16 + col] = acc.y + bb;
            A[(size_t)(n0w + quad*4 + 2)*64 + nt*16 + col] = acc.z + bb;
            A[(size_t)(n0w + quad*4 + 3)*64 + nt*16 + col] = acc.w + bb;
        } else {
            Bm[(size_t)(n0w + quad*4 + 0)*64 + (nt-4)*16 + col] = acc.x;
            Bm[(size_t)(n0w + quad*4 + 1)*64 + (nt-4)*16 + col] = acc.y;
            Bm[(size_t)(n0w + quad*4 + 2)*64 + (nt-4)*16 + col] = acc.z;
            Bm[(size_t)(n0w + quad*4 + 3)*64 + (nt-4)*16 + col] = acc.w;
        }
    }
}

// Fused edge+update: block = 16 targets; 4 waves x 4 targets edge MFMA -> LDS agg tile;
// wave 0 then runs the 16-node update MLP from LDS. No agg global round-trip.
__global__ __launch_bounds__(256, 4) void k_eu(
    const float* __restrict__ A, const float* __restrict__ Bm,
    const int* __restrict__ deg, const int* __restrict__ ssrc,
    const float* __restrict__ W2e, const float* __restrict__ B2e,
    float* __restrict__ h,
    const float* __restrict__ W1u, const float* __restrict__ B1u,
    const float* __restrict__ W2u, const float* __restrict__ B2u,
    float* __restrict__ gout)
{
    alignas(16) __shared__ _Float16 sW1u[8192];   // u1 packed [ks4][nt4][qd4][col16][j8]
    alignas(16) __shared__ _Float16 sW2u[4096];   // u2 packed [ks2][nt4][qd4][col16][j8]
    alignas(16) __shared__ _Float16 sM2[4096];    // m2 packed (edge W2)
    alignas(16) __shared__ float sAgg[16*68];     // agg tile, reused as hid tile
    for (int idx = threadIdx.x; idx < 8192; idx += 256) {
        int k = idx >> 6, n = idx & 63;
        int ks = k >> 5, qd = (k >> 3) & 3, j = k & 7, nt = n >> 4, cl = n & 15;
        sW1u[(((ks*4+nt)*4+qd)*16+cl)*8 + j] = (_Float16)W1u[idx];
    }
    for (int idx = threadIdx.x; idx < 4096; idx += 256) {
        int k = idx >> 6, n = idx & 63;
        int ks = k >> 5, qd = (k >> 3) & 3, j = k & 7, nt = n >> 4, cl = n & 15;
        sW2u[(((ks*4+nt)*4+qd)*16+cl)*8 + j] = (_Float16)W2u[idx];
        sM2 [(((ks*4+nt)*4+qd)*16+cl)*8 + j] = (_Float16)W2e[idx];
    }
    __syncthreads();
    const int lane = threadIdx.x & 63;
    const int wv = threadIdx.x >> 6;
    const int col = lane & 15, quad = lane >> 4;
    F8 bfe[4][2];
    #pragma unroll
    for (int nt = 0; nt < 4; nt++)
        #pragma unroll
        for (int ks = 0; ks < 2; ks++)
            bfe[nt][ks].v = *(const f16x8*)&sM2[(((ks*4+nt)*4+quad)*16+col)*8];
    float b2e[4];
    #pragma unroll
    for (int nt = 0; nt < 4; nt++) b2e[nt] = B2e[nt*16 + col];

    const int t_base = blockIdx.x * 16;
    // prefetch ssrc rows + degrees for this wave's 4 targets
    int cnts[4], sv[4];
    #pragma unroll
    for (int m = 0; m < 4; m++) {
        int t = t_base + wv*4 + m;
        cnts[m] = deg[t];
        sv[m] = ssrc[t*64 + lane];
    }
    #pragma unroll
    for (int m = 0; m < 4; m++) {
        int t = t_base + wv*4 + m;
        int cnt = cnts[m] > 64 ? 64 : cnts[m];
        const float* ar = &A[(size_t)t*64 + quad*8];
        float4 a0 = *(const float4*)&ar[0];
        float4 a1 = *(const float4*)&ar[4];
        float4 a2 = *(const float4*)&ar[32];
        float4 a3 = *(const float4*)&ar[36];
        float cs[4] = {0.f, 0.f, 0.f, 0.f};
        for (int s0 = 0; s0 < cnt; s0 += 16) {
            int v = cnt - s0;
            int cc = col < v-1 ? col : v-1;
            int sr = __shfl(sv[m], s0 + cc, 64);
            const float* br = &Bm[(size_t)sr*64 + quad*8];
            float4 b0 = *(const float4*)&br[0];
            float4 b1 = *(const float4*)&br[4];
            float4 b2_ = *(const float4*)&br[32];
            float4 b3 = *(const float4*)&br[36];
            F8 af0, af1;
            af0.u[0] = pk2h(fmaxf(a0.x+b0.x,0.f), fmaxf(a0.y+b0.y,0.f));
            af0.u[1] = pk2h(fmaxf(a0.z+b0.z,0.f), fmaxf(a0.w+b0.w,0.f));
            af0.u[2] = pk2h(fmaxf(a1.x+b1.x,0.f), fmaxf(a1.y+b1.y,0.f));
            af0.u[3] = pk2h(fmaxf(a1.z+b1.z,0.f), fmaxf(a1.w+b1.w,0.f));
            af1.u[0] = pk2h(fmaxf(a2.x+b2_.x,0.f), fmaxf(a2.y+b2_.y,0.f));
            af1.u[1] = pk2h(fmaxf(a2.z+b2_.z,0.f), fmaxf(a2.w+b2_.w,0.f));
            af1.u[2] = pk2h(fmaxf(a3.x+b3.x,0.f), fmaxf(a3.y+b3.y,0.f));
            af1.u[3] = pk2h(fmaxf(a3.z+b3.z,0.f), fmaxf(a3.w+b3.w,0.f));
            #pragma unroll
            for (int nt = 0; nt < 4; nt++) {
                f32x4 acc = __builtin_amdgcn_mfma_f32_16x16x32_f16(
                                af0.v, bfe[nt][0].v, (f32x4){0.f,0.f,0.f,0.f}, 0, 0, 0);
                acc = __builtin_amdgcn_mfma_f32_16x16x32_f16(
                                af1.v, bfe[nt][1].v, acc, 0, 0, 0);
                float r0 = (quad*4+0 < v) ? fmaxf(acc.x + b2e[nt], 0.f) : 0.f;
                float r1 = (quad*4+1 < v) ? fmaxf(acc.y + b2e[nt], 0.f) : 0.f;
                float r2 = (quad*4+2 < v) ? fmaxf(acc.z + b2e[nt], 0.f) : 0.f;
                float r3 = (quad*4+3 < v) ? fmaxf(acc.w + b2e[nt], 0.f) : 0.f;
                cs[nt] += (r0 + r1) + (r2 + r3);
            }
        }
        #pragma unroll
        for (int nt = 0; nt < 4; nt++) {
            float vv = cs[nt];
            vv += __shfl_down(vv, 32, 64);
            vv += __shfl_down(vv, 16, 64);
            cs[nt] = vv;
        }
        if (lane < 16) {
            sAgg[(wv*4+m)*68 +  0 + lane] = cs[0];
            sAgg[(wv*4+m)*68 + 16 + lane] = cs[1];
            sAgg[(wv*4+m)*68 + 32 + lane] = cs[2];
            sAgg[(wv*4+m)*68 + 48 + lane] = cs[3];
        }
    }
    __syncthreads();
    if (wv == 0) {
        const int n0w = t_base;
        const float* hp = &h[(size_t)(n0w+col)*64 + quad*8];
        float4 h0 = *(const float4*)&hp[0];
        float4 h1 = *(const float4*)&hp[4];
        float4 h2 = *(const float4*)&hp[32];
        float4 h3 = *(const float4*)&hp[36];
        const float* ap = &sAgg[col*68 + quad*8];
        float4 g0 = *(const float4*)&ap[0];
        float4 g1 = *(const float4*)&ap[4];
        float4 g2 = *(const float4*)&ap[32];
        float4 g3 = *(const float4*)&ap[36];
        F8 af[4];
        af[0].u[0] = pk2h(h0.x, h0.y); af[0].u[1] = pk2h(h0.z, h0.w);
        af[0].u[2] = pk2h(h1.x, h1.y); af[0].u[3] = pk2h(h1.z, h1.w);
        af[1].u[0] = pk2h(h2.x, h2.y); af[1].u[1] = pk2h(h2.z, h2.w);
        af[1].u[2] = pk2h(h3.x, h3.y); af[1].u[3] = pk2h(h3.z, h3.w);
        af[2].u[0] = pk2h(g0.x, g0.y); af[2].u[1] = pk2h(g0.z, g0.w);
        af[2].u[2] = pk2h(g1.x, g1.y); af[2].u[3] = pk2h(g1.z, g1.w);
        af[3].u[0] = pk2h(g2.x, g2.y); af[3].u[1] = pk2h(g2.z, g2.w);
        af[3].u[2] = pk2h(g3.x, g3.y); af[3].u[3] = pk2h(g3.z, g3.w);
        float b1v[4], b2v[4];
        #pragma unroll
        for (int nt = 0; nt < 4; nt++) { b1v[nt] = B1u[nt*16+col]; b2v[nt] = B2u[nt*16+col]; }
        #pragma unroll
        for (int nt = 0; nt < 4; nt++) {
            f32x4 acc = {0.f,0.f,0.f,0.f};
            #pragma unroll
            for (int ks = 0; ks < 4; ks++) {
                F8 bf; bf.v = *(const f16x8*)&sW1u[(((ks*4+nt)*4+quad)*16+col)*8];
                acc = __builtin_amdgcn_mfma_f32_16x16x32_f16(af[ks].v, bf.v, acc, 0, 0, 0);
            }
            sAgg[(quad*4+0)*68 + nt*16+col] = fmaxf(acc.x + b1v[nt], 0.f);
            sAgg[(quad*4+1)*68 + nt*16+col] = fmaxf(acc.y + b1v[nt], 0.f);
            sAgg[(quad*4+2)*68 + nt*16+col] = fmaxf(acc.z + b1v[nt], 0.f);
            sAgg[(quad*4+3)*68 + nt*16+col] = fmaxf(acc.w + b1v[nt], 0.f);
        }
        const float* hr = &sAgg[col*68 + quad*8];
        float4 q0 = *(const float4*)&hr[0];
        float4 q1 = *(const float4*)&hr[4];
        float4 q2 = *(const float4*)&hr[32];
        float4 q3 = *(const float4*)&hr[36];
        F8 e0, e1;
        e0.u[0] = pk2h(q0.x, q0.y); e0.u[1] = pk2h(q0.z, q0.w);
        e0.u[2] = pk2h(q1.x, q1.y); e0.u[3] = pk2h(q1.z, q1.w);
        e1.u[0] = pk2h(q2.x, q2.y); e1.u[1] = pk2h(q2.z, q2.w);
        e1.u[2] = pk2h(q3.x, q3.y); e1.u[3] = pk2h(q3.z, q3.w);
        float ss[4], sq[4];
        #pragma unroll
        for (int nt = 0; nt < 4; nt++) {
            f32x4 acc = {0.f,0.f,0.f,0.f};
            F8 bf; bf.v = *(const f16x8*)&sW2u[(((0*4+nt)*4+quad)*16+col)*8];
            acc = __builtin_amdgcn_mfma_f32_16x16x32_f16(e0.v, bf.v, acc, 0, 0, 0);
            bf.v = *(const f16x8*)&sW2u[(((1*4+nt)*4+quad)*16+col)*8];
            acc = __builtin_amdgcn_mfma_f32_16x16x32_f16(e1.v, bf.v, acc, 0, 0, 0);
            float o0 = fmaxf(acc.x + b2v[nt], 0.f);
            float o1 = fmaxf(acc.y + b2v[nt], 0.f);
            float o2 = fmaxf(acc.z + b2v[nt], 0.f);
            float o3 = fmaxf(acc.w + b2v[nt], 0.f);
            h[(size_t)(n0w + quad*4 + 0)*64 + nt*16 + col] = o0;
            h[(size_t)(n0w + quad*4 + 1)*64 + nt*16 + col] = o1;
            h[(size_t)(n0w + quad*4 + 2)*64 + nt*16 + col] = o2;
            h[(size_t)(n0w + quad*4 + 3)*64 + nt*16 + col] = o3;
            ss[nt] = (o0 + o1) + (o2 + o3);
            sq[nt] = (o0*o0 + o1*o1) + (o2*o2 + o3*o3);
        }
        #pragma unroll
        for (int nt = 0; nt < 4; nt++) {
            float v = ss[nt];
            v += __shfl_down(v, 32, 64); v += __shfl_down(v, 16, 64);
            ss[nt] = v;
            float w2 = sq[nt];
            w2 += __shfl_down(w2, 32, 64); w2 += __shfl_down(w2, 16, 64);
            sq[nt] = w2;
        }
        if (lane < 16) {
            int b = (int)(blockIdx.x >> 7);
            #pragma unroll
            for (int nt = 0; nt < 4; nt++) {
                atomicAdd(&gout[b*64 + nt*16 + lane], ss[nt]);
                atomicAdd(&gout[NB*64 + b*64 + nt*16 + lane], sq[nt]);
            }
        }
    }
}

// MFMA pre (layers 1,2): normalize h (write back), A = h@W1a+b1, B = h@W1b; zero gz.
__global__ __launch_bounds__(256) void k_preM(
    float* __restrict__ h,
    const float* __restrict__ W1, const float* __restrict__ B1,
    float* __restrict__ A, float* __restrict__ Bm,
    const float* __restrict__ gin, float* __restrict__ gz)
{
    alignas(16) __shared__ _Float16 sWp[8192];   // [ks2][nt8][qd4][col16][j8]
    __shared__ float sMean[64], sRstd[64];
    for (int idx = threadIdx.x; idx < 8192; idx += 256) {
        int k = idx >> 7, n = idx & 127;
        float val = (n < 64) ? W1[k*64 + n] : W1[(64+k)*64 + (n-64)];
        int ks = k >> 5, qd = (k >> 3) & 3, j = k & 7, nt = n >> 4, cl = n & 15;
        sWp[(((ks*8+nt)*4+qd)*16+cl)*8 + j] = (_Float16)val;
    }
    if (threadIdx.x < 64) {
        int b = (int)(blockIdx.x >> 5);
        float s  = gin[b*64 + threadIdx.x];
        float qq = gin[NB*64 + b*64 + threadIdx.x];
        float mean = s * (1.f/NS);
        float var  = qq * (1.f/NS) - mean*mean;
        sMean[threadIdx.x] = mean;
        sRstd[threadIdx.x] = rsqrtf(var + EPSF);
    }
    if (blockIdx.x == 0)
        for (int i = threadIdx.x; i < 2*NB*64; i += 256) gz[i] = 0.f;
    __syncthreads();
    const int lane = threadIdx.x & 63;
    const int wv = threadIdx.x >> 6;
    const int col = lane & 15, quad = lane >> 4;
    const int n0w = blockIdx.x*64 + wv*16;
    float* hp = &h[(size_t)(n0w+col)*64 + quad*8];
    float xv[16];
    *(float4*)&xv[0]  = *(const float4*)&hp[0];
    *(float4*)&xv[4]  = *(const float4*)&hp[4];
    *(float4*)&xv[8]  = *(const float4*)&hp[32];
    *(float4*)&xv[12] = *(const float4*)&hp[36];
    #pragma unroll
    for (int t2 = 0; t2 < 8; t2++) {
        int f = quad*8 + t2;
        xv[t2] = (xv[t2] - sMean[f]) * sRstd[f];
    }
    #pragma unroll
    for (int t2 = 0; t2 < 8; t2++) {
        int f = 32 + quad*8 + t2;
        xv[8+t2] = (xv[8+t2] - sMean[f]) * sRstd[f];
    }
    *(float4*)&hp[0]  = *(float4*)&xv[0];
    *(float4*)&hp[4]  = *(float4*)&xv[4];
    *(float4*)&hp[32] = *(float4*)&xv[8];
    *(float4*)&hp[36] = *(float4*)&xv[12];
    F8 af0, af1;
    af0.u[0] = pk2h(xv[0],  xv[1]);  af0.u[1] = pk2h(xv[2],  xv[3]);
    af0.u[2] = pk2h(xv[4],  xv[5]);  af0.u[3] = pk2h(xv[6],  xv[7]);
    af1.u[0] = pk2h(xv[8],  xv[9]);  af1.u[1] = pk2h(xv[10], xv[11]);
    af1.u[2] = pk2h(xv[12], xv[13]); af1.u[3] = pk2h(xv[14], xv[15]);
    float b1v[4];
    #pragma unroll
    for (int nt = 0; nt < 4; nt++) b1v[nt] = B1[nt*16+col];
    #pragma unroll
    for (int nt = 0; nt < 8; nt++) {
        f32x4 acc = {0.f,0.f,0.f,0.f};
        F8 bf; bf.v = *(const f16x8*)&sWp[(((0*8+nt)*4+quad)*16+col)*8];
        acc = __builtin_amdgcn_mfma_f32_16x16x32_f16(af0.v, bf.v, acc, 0, 0, 0);
        bf.v = *(const f16x8*)&sWp[(((1*8+nt)*4+quad)*16+col)*8];
        acc = __builtin_amdgcn_mfma_f32_16x16x32_f16(af1.v, bf.v, acc, 0, 0, 0);
        if (nt < 4) {
            float bb = b1v[nt];
            A[(size_t)(n0w + quad*4 + 0)*64 + nt*16 + col] = acc.x + bb;
            A[(size_t)(n0w + quad*4 + 1)*64 + nt*16 + col] = acc.y + bb;
            A[(size_t)(n0w + quad*4 + 2)*64 + nt*16 + col] = acc.z + bb;
            A[(size_t)(n0w + quad*4 + 3)*64 + nt*16 + col] = acc.w + bb;
        } else {
            Bm[(size_t)(n0w + quad*4 + 0)*64 + (nt-4)*16 + col] = acc.x;
            Bm[(size_t)(n0w + quad*4 + 1)*64 + (nt-4)*16 + col] = acc.y;
            Bm[(size_t)(n0w + quad*4 + 2)*64 + (nt-4)*16 + col] = acc.z;
            Bm[(size_t)(n0w + quad*4 + 3)*64 + (nt-4)*16 + col] = acc.w;
        }
    }
}

// Fused: instance-norm + decode + sigmoid + t2-term reduction
__global__ __launch_bounds__(256) void k_dec(
    const float* __restrict__ h, const float* __restrict__ Wd, const float* __restrict__ bd,
    const float* __restrict__ g, float* __restrict__ xbuf, float* __restrict__ out1,
    float* __restrict__ accum)
{
    int n = blockIdx.x*256 + threadIdx.x;
    int b = n >> 11;
    __shared__ float sM[64], sR[64];
    __shared__ float sWd[256];
    if (threadIdx.x < 64) {
        float s  = g[b*64 + threadIdx.x];
        float qq = g[NB*64 + b*64 + threadIdx.x];
        float mean = s * (1.f/NS);
        float var  = qq * (1.f/NS) - mean*mean;
        sM[threadIdx.x] = mean; sR[threadIdx.x] = rsqrtf(var + EPSF);
    }
    for (int i = threadIdx.x; i < 256; i += 256) sWd[i] = Wd[i];
    __syncthreads();
    float a0 = bd[0], a1 = bd[1], a2 = bd[2], a3 = bd[3];
    const float* hr = h + (size_t)n*64;
    #pragma unroll 8
    for (int k = 0; k < 64; k++) {
        float v = (hr[k] - sM[k]) * sR[k];
        a0 = fmaf(v, sWd[k*4+0], a0);
        a1 = fmaf(v, sWd[k*4+1], a1);
        a2 = fmaf(v, sWd[k*4+2], a2);
        a3 = fmaf(v, sWd[k*4+3], a3);
    }
    float4 o;
    o.x = 1.f/(1.f + expf(-a0));
    o.y = 1.f/(1.f + expf(-a1));
    o.z = 1.f/(1.f + expf(-a2));
    o.w = 1.f/(1.f + expf(-a3));
    *(float4*)&xbuf[(size_t)n*4] = o;
    out1[n*4+0] = o.x; out1[n*4+1] = o.y; out1[n*4+2] = o.z; out1[n*4+3] = o.w;
    float p = (1.f-o.x*o.x)*(1.f-o.y*o.y)*(1.f-o.z*o.z)*(1.f-o.w*o.w);
    for (int offs = 32; offs; offs >>= 1) p += __shfl_down(p, offs, 64);
    __shared__ float ws[4];
    if ((threadIdx.x & 63) == 0) ws[threadIdx.x >> 6] = p;
    __syncthreads();
    if (threadIdx.x == 0) atomicAdd(&accum[0], ws[0]+ws[1]+ws[2]+ws[3]);
}

// t3 pairwise term + final loss via last-block ticket
__global__ __launch_bounds__(256) void k_t3(const float* __restrict__ X,
                                            float* __restrict__ accum,
                                            float* __restrict__ out)
{
    int b = blockIdx.x >> 5, c = blockIdx.x & 31;
    __shared__ float sX[NS*4];
    const float* Xb = X + (size_t)b*NS*4;
    for (int idx = threadIdx.x; idx < NS*4; idx += 256) sX[idx] = Xb[idx];
    __syncthreads();
    const float4* sX4 = (const float4*)sX;
    int il = threadIdx.x & 63, wv = threadIdx.x >> 6;
    float4 xi = sX4[c*64 + il];
    float acc = 0.f;
    #pragma unroll 4
    for (int s = 0; s < 512; s++) {
        float4 xj = sX4[wv*512 + s];
        acc += (1.f - fmaxf(xi.x, xj.x)) * (1.f - fmaxf(xi.y, xj.y))
             * (1.f - fmaxf(xi.z, xj.z)) * (1.f - fmaxf(xi.w, xj.w));
    }
    for (int offs = 32; offs; offs >>= 1) acc += __shfl_down(acc, offs, 64);
    __shared__ float ws[4];
    if (il == 0) ws[wv] = acc;
    __syncthreads();
    if (threadIdx.x == 0) {
        atomicAdd(&accum[1], ws[0]+ws[1]+ws[2]+ws[3]);
        __threadfence();
        unsigned t = atomicAdd((unsigned int*)&accum[2], 1u);
        if (t == (unsigned)(NB*32 - 1)) {
            float A2 = __hip_atomic_load(&accum[0], __ATOMIC_ACQUIRE, __HIP_MEMORY_SCOPE_AGENT);
            float A3 = __hip_atomic_load(&accum[1], __ATOMIC_ACQUIRE, __HIP_MEMORY_SCOPE_AGENT);
            float t1 = 1.f/81.f;
            float t2 = (2.f/(NS*16.f)) * (A2 / NB);
            float t3 = (A3 / ((float)NS*(float)NS)) / NB;
            out[0] = t1 - t2 + t3;
        }
    }
}

extern "C" void kernel_launch(void* const* d_in, const int* in_sizes, int n_in,
                              void* d_out, int out_size, void* d_ws, size_t ws_size,
                              hipStream_t stream)
{
    const float* x     = (const float*)d_in[0];
    const int*   ei    = (const int*)d_in[1];
    const float* enc_w = (const float*)d_in[2];
    const float* enc_b = (const float*)d_in[3];
    const float* m1w   = (const float*)d_in[4];
    const float* m1b   = (const float*)d_in[5];
    const float* m2w   = (const float*)d_in[6];
    const float* m2b   = (const float*)d_in[7];
    const float* u1w   = (const float*)d_in[8];
    const float* u1b   = (const float*)d_in[9];
    const float* u2w   = (const float*)d_in[10];
    const float* u2b   = (const float*)d_in[11];
    const float* dw    = (const float*)d_in[12];
    const float* db    = (const float*)d_in[13];
    float* out = (float*)d_out;

    float* h    = (float*)d_ws;            // NN*64
    float* Apre = h    + NN*64;            // NN*64
    float* Bpre = Apre + NN*64;            // NN*64
    float* g0   = Bpre + NN*64;            // 2*NB*64
    float* g1   = g0   + 2*NB*64;          // 2*NB*64
    float* acc  = g1   + 2*NB*64;          // 4
    int*   deg  = (int*)(acc + 4);         // NN
    int*   ssrc = deg + NN;                // NN*64
    float* xbuf = Apre;                    // alias (Apre dead after last eu)

    const int* srcv = ei;
    const int* tgtv = ei + NE;
    float* gbuf[2] = {g0, g1};

    k_init<<<NN/256, 256, 0, stream>>>(deg, acc);
    k_pre0M<<<NN/64, 256, 0, stream>>>(x, enc_w, enc_b, h, m1w, m1b,
                                       Apre, Bpre, g0, srcv, tgtv, deg, ssrc);

    for (int l = 0; l < 3; l++) {
        if (l)
            k_preM<<<NN/64, 256, 0, stream>>>(h, m1w + l*128*64, m1b + l*64,
                                              Apre, Bpre,
                                              gbuf[(l+1)&1], gbuf[l&1]);
        k_eu<<<NN/16, 256, 0, stream>>>(Apre, Bpre, deg, ssrc,
                                        m2w + l*64*64, m2b + l*64,
                                        h,
                                        u1w + l*128*64, u1b + l*64,
                                        u2w + l*64*64,  u2b + l*64,
                                        gbuf[l&1]);
    }

    k_dec<<<NN/256, 256, 0, stream>>>(h, dw, db, g0, xbuf, out + 1, acc);
    k_t3<<<NB*32, 256, 0, stream>>>(xbuf, acc, out);
}